// Round 10
// baseline (463.316 us; speedup 1.0000x reference)
//
#include <hip/hip_runtime.h>
#include <math.h>

// LSTM fused: H=32, D=1, B=4096, T=1024 — register-resident recurrence,
// bpermute h-exchange (no LDS round-trip on the critical path).
//
// R8/R9 law: per-SIMD throughput = step-chain-latency / batches-per-SIMD;
// batches/SIMD is capped at 4 (4096/1024), so the only lever is the chain.
// R9's chain (~915 cyc): ds_write h -> drain -> ds_read bf (~200-250) +
// MFMA (~70) + extract (~30) + act (~300). This round removes the LDS
// round-trip:
//   - Tile-permuted A: tile tau=2g+p holds W_hh rows 32g+2m+p, so lane
//     (q,n) gets all 4 gates of units (2w, 2w+1), w=4q+r  (r=n>>2, b=n&3).
//   - After act, pack (h_even,h_odd) with ONE v_cvt_pkrtz_f16_f32.
//   - Next B-frag: 4 parallel ds_bpermute_b32 (slot j <- lane 16q+b+4j),
//     single crossbar level, conflict-free, constant addresses.
// 256 blocks x 4 waves = 1024 waves = 1/SIMD; zero barriers; x in LDS
// (off-chain). Layout provenance: A[m=lane&15][k=8q+j], B[k=8q+j][n=lane&15],
// C col=lane&15 row=4q+reg (validated R7-R9, absmax 9.8e-4).

#define HH 32
#define TT 1024
#define BPW 4               // batches per wave
#define WPB 4               // waves per block
#define BPB (BPW * WPB)     // 16
#define NT 256

typedef _Float16 half2_t __attribute__((ext_vector_type(2)));
typedef _Float16 half8   __attribute__((ext_vector_type(8)));
typedef float    f32x4   __attribute__((ext_vector_type(4)));
typedef int      int4v   __attribute__((ext_vector_type(4)));

__device__ __forceinline__ float fast_sigmoid(float x) {
    float e = __builtin_amdgcn_exp2f(x * -1.4426950408889634f);
    return __builtin_amdgcn_rcpf(1.0f + e);
}

__device__ __forceinline__ float fast_tanh(float x) {
    float e = __builtin_amdgcn_exp2f(x * -2.8853900817779268f);
    return fmaf(2.0f, __builtin_amdgcn_rcpf(1.0f + e), -1.0f);
}

__global__ __attribute__((amdgpu_flat_work_group_size(NT, NT),
                          amdgpu_waves_per_eu(1, 2)))
void lstm_bp(const float* __restrict__ x,
             const float* __restrict__ W_ih,
             const float* __restrict__ W_hh,
             const float* __restrict__ b_ih,
             const float* __restrict__ b_hh,
             const float* __restrict__ fc_W,
             const float* __restrict__ fc_b,
             float* __restrict__ out)
{
    __shared__ _Float16 xw[WPB][BPW * TT];   // 32 KB: x fp16, wave-private

    const int tid  = threadIdx.x;
    const int wv   = tid >> 6;
    const int lane = tid & 63;
    const int q    = lane >> 4;          // quad
    const int n    = lane & 15;          // MFMA col
    const int b    = n & 3;              // this lane's batch (0..3)
    const int r    = n >> 2;             // C reg component
    const int w    = 4 * q + r;          // unit-pair index 0..15
    const int ue   = 2 * w;              // even unit of this lane
    const int uo   = ue + 1;             // odd unit
    const int gb0  = blockIdx.x * BPB + wv * BPW;

    // ---- stage this wave's 4 x-rows into LDS as fp16 (wave-private) ----
    {
        const float4* xg = (const float4*)(x + (size_t)gb0 * TT);
        #pragma unroll
        for (int it = 0; it < (BPW * TT / 4) / 64; ++it) {
            const float4 v = xg[it * 64 + lane];
            _Float16* dst = &xw[wv][(it * 64 + lane) * 4];
            dst[0] = (_Float16)v.x; dst[1] = (_Float16)v.y;
            dst[2] = (_Float16)v.z; dst[3] = (_Float16)v.w;
        }
    }

    // ---- A-fragments, pair-permuted: tile tau=2g+p row m = W_hh row 32g+2m+p.
    //      Then C: lane (q,n) reg r of tile 2g+p = gate g, unit 2(4q+r)+p. ----
    half8 af[8];
    #pragma unroll
    for (int g = 0; g < 4; ++g) {
        #pragma unroll
        for (int p = 0; p < 2; ++p) {
            const float* arow = W_hh + (size_t)(32 * g + 2 * n + p) * HH + 8 * q;
            #pragma unroll
            for (int j = 0; j < 8; ++j)
                af[2 * g + p][j] = (_Float16)arow[j];
        }
    }

    // ---- per-lane act constants for states (b,ue) and (b,uo) ----
    float wxE[4], bbE[4], wxO[4], bbO[4];
    #pragma unroll
    for (int g = 0; g < 4; ++g) {
        wxE[g] = W_ih[g * HH + ue];
        bbE[g] = b_ih[g * HH + ue] + b_hh[g * HH + ue];
        wxO[g] = W_ih[g * HH + uo];
        bbO[g] = b_ih[g * HH + uo] + b_hh[g * HH + uo];
    }

    // ---- bpermute source addresses: B-frag u32 slot j <- lane 16q + b + 4j ----
    const int a0 = (16 * q + b + 0)  * 4;
    const int a1 = (16 * q + b + 4)  * 4;
    const int a2 = (16 * q + b + 8)  * 4;
    const int a3 = (16 * q + b + 12) * 4;

    float ce = 0.0f, he = 0.0f, co = 0.0f, ho = 0.0f;
    int pki = 0;                          // packed (h_ue, h_uo) fp16x2

    const _Float16* xr = &xw[wv][b * TT];
    const bool rb0 = (r & 1) != 0;
    const bool rb1 = (r & 2) != 0;

    #pragma unroll 2
    for (int t = 0; t < TT; ++t) {
        // ---- h exchange: 4 parallel crossbar pulls (no LDS round-trip) ----
        const int s0 = __builtin_amdgcn_ds_bpermute(a0, pki);
        const int s1 = __builtin_amdgcn_ds_bpermute(a1, pki);
        const int s2 = __builtin_amdgcn_ds_bpermute(a2, pki);
        const int s3 = __builtin_amdgcn_ds_bpermute(a3, pki);
        int4v bi; bi[0] = s0; bi[1] = s1; bi[2] = s2; bi[3] = s3;
        const half8 bf = __builtin_bit_cast(half8, bi);

        const f32x4 zero = {0.0f, 0.0f, 0.0f, 0.0f};
        f32x4 acc[8];
        #pragma unroll
        for (int tau = 0; tau < 8; ++tau)
            acc[tau] = __builtin_amdgcn_mfma_f32_16x16x32_f16(
                           af[tau], bf, zero, 0, 0, 0);

        // ---- extract: gate g of ue = acc[2g][r], of uo = acc[2g+1][r] ----
        float ve[4], vo[4];
        #pragma unroll
        for (int g = 0; g < 4; ++g) {
            const f32x4 lo = acc[2 * g];
            const f32x4 hi = acc[2 * g + 1];
            const float l01 = rb0 ? lo[1] : lo[0];
            const float l23 = rb0 ? lo[3] : lo[2];
            ve[g] = rb1 ? l23 : l01;
            const float h01 = rb0 ? hi[1] : hi[0];
            const float h23 = rb0 ? hi[3] : hi[2];
            vo[g] = rb1 ? h23 : h01;
        }

        // ---- act: two independent states per lane ----
        const float xv = (float)xr[t];
        const float pe0 = fmaf(xv, wxE[0], ve[0] + bbE[0]);
        const float pe1 = fmaf(xv, wxE[1], ve[1] + bbE[1]);
        const float pe2 = fmaf(xv, wxE[2], ve[2] + bbE[2]);
        const float pe3 = fmaf(xv, wxE[3], ve[3] + bbE[3]);
        const float po0 = fmaf(xv, wxO[0], vo[0] + bbO[0]);
        const float po1 = fmaf(xv, wxO[1], vo[1] + bbO[1]);
        const float po2 = fmaf(xv, wxO[2], vo[2] + bbO[2]);
        const float po3 = fmaf(xv, wxO[3], vo[3] + bbO[3]);

        const float giE = fast_sigmoid(pe0);
        const float giO = fast_sigmoid(po0);
        const float gfE = fast_sigmoid(pe1);
        const float gfO = fast_sigmoid(po1);
        const float ggE = fast_tanh(pe2);
        const float ggO = fast_tanh(po2);
        const float goE = fast_sigmoid(pe3);
        const float goO = fast_sigmoid(po3);
        ce = fmaf(gfE, ce, giE * ggE);
        co = fmaf(gfO, co, giO * ggO);
        he = goE * fast_tanh(ce);
        ho = goO * fast_tanh(co);

        // ---- pack for next step's exchange (1 inst) ----
        pki = __builtin_bit_cast(int, __builtin_amdgcn_cvt_pkrtz(he, ho));
    }

    // ---- epilogue: out[b] = fc_W . h + fc_b; reduce lanes with same b ----
    float pr = he * fc_W[ue] + ho * fc_W[uo];
    #pragma unroll
    for (int m = 4; m <= 32; m <<= 1)
        pr += __shfl_xor(pr, m, 64);         // over r (bits 2,3) and q (4,5)
    if (lane < 4)
        out[gb0 + lane] = pr + fc_b[0];      // lane = b at q=0,r=0
}

extern "C" void kernel_launch(void* const* d_in, const int* in_sizes, int n_in,
                              void* d_out, int out_size, void* d_ws, size_t ws_size,
                              hipStream_t stream) {
    const float* x    = (const float*)d_in[0];
    const float* W_ih = (const float*)d_in[1];
    const float* W_hh = (const float*)d_in[2];
    const float* b_ih = (const float*)d_in[3];
    const float* b_hh = (const float*)d_in[4];
    const float* fc_W = (const float*)d_in[5];
    const float* fc_b = (const float*)d_in[6];
    float* out = (float*)d_out;

    const int B = in_sizes[0] / TT;   // 4096 (D == 1)
    dim3 grid(B / BPB), block(NT);
    lstm_bp<<<grid, block, 0, stream>>>(x, W_ih, W_hh, b_ih, b_hh,
                                        fc_W, fc_b, out);
}

// Round 11
// 430.001 us; speedup vs baseline: 1.0775x; 1.0775x over previous
//
#include <hip/hip_runtime.h>
#include <math.h>

// LSTM fused: H=32, D=1, B=4096, T=1024 — DPP quad_perm h-exchange (pure VALU).
//
// R8-R10 law: wall = per-step serial chain (~1000 cyc), batches/SIMD capped
// at 4. R10 showed ds_bpermute is NOT cheaper than LDS r/w (both DS pipe +
// lgkmcnt(0) at chain head). This round removes the DS pipe from the chain:
//   - Lane (q,n): batch b = n>>2, slot rho = n&3, owns unit pair w = 4q+rho
//     (units 2w, 2w+1). The 4 lanes holding batch b's pairs are the
//     CONTIGUOUS QUAD n in [4b,4b+4) -> B-frag slot j comes from quad-lane j
//     of the lane's own quad: 4x v_mov_b32_dpp quad_perm:[j,j,j,j].
//     Exchange = 1 cvt_pkrtz + 4 DPP movs, VALU pipe, no waitcnt.
//   - x: one prefetched ds_read_b128 per 8 steps (off-chain).
//   - A tile-permuted as R10 (tau=2g+p holds W_hh rows 32g+2m+p), extraction
//     cndmask bools re-keyed to rho. Act math identical to R9/R10.
// 256 blocks x 4 waves = 1024 waves = 1/SIMD; zero barriers.

#define HH 32
#define TT 1024
#define BPW 4               // batches per wave
#define WPB 4               // waves per block
#define BPB (BPW * WPB)     // 16
#define NT 256

typedef _Float16 half8 __attribute__((ext_vector_type(8)));
typedef float    f32x4 __attribute__((ext_vector_type(4)));
typedef int      int4v __attribute__((ext_vector_type(4)));

__device__ __forceinline__ float fast_sigmoid(float x) {
    float e = __builtin_amdgcn_exp2f(x * -1.4426950408889634f);
    return __builtin_amdgcn_rcpf(1.0f + e);
}

__device__ __forceinline__ float fast_tanh(float x) {
    float e = __builtin_amdgcn_exp2f(x * -2.8853900817779268f);
    return fmaf(2.0f, __builtin_amdgcn_rcpf(1.0f + e), -1.0f);
}

__global__ __attribute__((amdgpu_flat_work_group_size(NT, NT),
                          amdgpu_waves_per_eu(1, 2)))
void lstm_dpp(const float* __restrict__ x,
              const float* __restrict__ W_ih,
              const float* __restrict__ W_hh,
              const float* __restrict__ b_ih,
              const float* __restrict__ b_hh,
              const float* __restrict__ fc_W,
              const float* __restrict__ fc_b,
              float* __restrict__ out)
{
    __shared__ _Float16 xw[WPB][BPW * TT];   // 32 KB: x fp16, wave-private

    const int tid  = threadIdx.x;
    const int wv   = tid >> 6;
    const int lane = tid & 63;
    const int q    = lane >> 4;          // quad row group
    const int n    = lane & 15;          // MFMA col
    const int b    = n >> 2;             // this lane's batch (0..3)
    const int rho  = n & 3;              // owned slot & C reg component
    const int w    = 4 * q + rho;        // owned unit pair
    const int ue   = 2 * w;
    const int uo   = ue + 1;
    const int gb0  = blockIdx.x * BPB + wv * BPW;

    // ---- stage this wave's 4 x-rows into LDS as fp16 (wave-private) ----
    {
        const float4* xg = (const float4*)(x + (size_t)gb0 * TT);
        #pragma unroll
        for (int it = 0; it < (BPW * TT / 4) / 64; ++it) {
            const float4 v = xg[it * 64 + lane];
            _Float16* dst = &xw[wv][(it * 64 + lane) * 4];
            dst[0] = (_Float16)v.x; dst[1] = (_Float16)v.y;
            dst[2] = (_Float16)v.z; dst[3] = (_Float16)v.w;
        }
    }

    // ---- A-fragments, pair-permuted (R10-validated): tile tau=2g+p,
    //      A row m (=n) = W_hh row 32g + 2m + p;  A[m][k=8q+j] ----
    half8 af[8];
    #pragma unroll
    for (int g = 0; g < 4; ++g) {
        #pragma unroll
        for (int p = 0; p < 2; ++p) {
            const float* arow = W_hh + (size_t)(32 * g + 2 * n + p) * HH + 8 * q;
            #pragma unroll
            for (int j = 0; j < 8; ++j)
                af[2 * g + p][j] = (_Float16)arow[j];
        }
    }

    // ---- per-lane act constants for states (b,ue) and (b,uo) ----
    float wxE[4], bbE[4], wxO[4], bbO[4];
    #pragma unroll
    for (int g = 0; g < 4; ++g) {
        wxE[g] = W_ih[g * HH + ue];
        bbE[g] = b_ih[g * HH + ue] + b_hh[g * HH + ue];
        wxO[g] = W_ih[g * HH + uo];
        bbO[g] = b_ih[g * HH + uo] + b_hh[g * HH + uo];
    }

    float ce = 0.0f, he = 0.0f, co = 0.0f, ho = 0.0f;
    int pki = 0;                          // packed (h_ue, h_uo) fp16x2

    const bool rb0 = (rho & 1) != 0;
    const bool rb1 = (rho & 2) != 0;

    const half8* xp = (const half8*)&xw[wv][b * TT];   // broadcast per quad
    half8 xcur = xp[0];

    #pragma unroll 1
    for (int tc = 0; tc < TT / 8; ++tc) {
        const half8 xv8 = xcur;
        xcur = xp[(tc + 1) & (TT / 8 - 1)];   // prefetch next chunk (off-chain)

        #pragma unroll
        for (int tt = 0; tt < 8; ++tt) {
            // ---- h exchange: 4 quad_perm broadcasts (pure VALU, no DS) ----
            const int s0 = __builtin_amdgcn_mov_dpp(pki, 0x00, 0xF, 0xF, true);
            const int s1 = __builtin_amdgcn_mov_dpp(pki, 0x55, 0xF, 0xF, true);
            const int s2 = __builtin_amdgcn_mov_dpp(pki, 0xAA, 0xF, 0xF, true);
            const int s3 = __builtin_amdgcn_mov_dpp(pki, 0xFF, 0xF, 0xF, true);
            int4v bi; bi[0] = s0; bi[1] = s1; bi[2] = s2; bi[3] = s3;
            const half8 bf = __builtin_bit_cast(half8, bi);

            const f32x4 zero = {0.0f, 0.0f, 0.0f, 0.0f};
            f32x4 acc[8];
            #pragma unroll
            for (int tau = 0; tau < 8; ++tau)
                acc[tau] = __builtin_amdgcn_mfma_f32_16x16x32_f16(
                               af[tau], bf, zero, 0, 0, 0);

            // ---- extract: gate g of ue = acc[2g][rho], uo = acc[2g+1][rho] ----
            float ve[4], vo[4];
            #pragma unroll
            for (int g = 0; g < 4; ++g) {
                const f32x4 lo = acc[2 * g];
                const f32x4 hi = acc[2 * g + 1];
                const float l01 = rb0 ? lo[1] : lo[0];
                const float l23 = rb0 ? lo[3] : lo[2];
                ve[g] = rb1 ? l23 : l01;
                const float h01 = rb0 ? hi[1] : hi[0];
                const float h23 = rb0 ? hi[3] : hi[2];
                vo[g] = rb1 ? h23 : h01;
            }

            // ---- act: two independent states per lane ----
            const float xv = (float)xv8[tt];
            const float pe0 = fmaf(xv, wxE[0], ve[0] + bbE[0]);
            const float pe1 = fmaf(xv, wxE[1], ve[1] + bbE[1]);
            const float pe2 = fmaf(xv, wxE[2], ve[2] + bbE[2]);
            const float pe3 = fmaf(xv, wxE[3], ve[3] + bbE[3]);
            const float po0 = fmaf(xv, wxO[0], vo[0] + bbO[0]);
            const float po1 = fmaf(xv, wxO[1], vo[1] + bbO[1]);
            const float po2 = fmaf(xv, wxO[2], vo[2] + bbO[2]);
            const float po3 = fmaf(xv, wxO[3], vo[3] + bbO[3]);

            const float giE = fast_sigmoid(pe0);
            const float giO = fast_sigmoid(po0);
            const float gfE = fast_sigmoid(pe1);
            const float gfO = fast_sigmoid(po1);
            const float ggE = fast_tanh(pe2);
            const float ggO = fast_tanh(po2);
            const float goE = fast_sigmoid(pe3);
            const float goO = fast_sigmoid(po3);
            ce = fmaf(gfE, ce, giE * ggE);
            co = fmaf(gfO, co, giO * ggO);
            he = goE * fast_tanh(ce);
            ho = goO * fast_tanh(co);

            // ---- pack for next step's exchange ----
            pki = __builtin_bit_cast(int, __builtin_amdgcn_cvt_pkrtz(he, ho));
        }
    }

    // ---- epilogue: out[b] = fc_W . h + fc_b; batch = lane bits 2,3 ----
    float pr = he * fc_W[ue] + ho * fc_W[uo];
    pr += __shfl_xor(pr, 1, 64);
    pr += __shfl_xor(pr, 2, 64);
    pr += __shfl_xor(pr, 16, 64);
    pr += __shfl_xor(pr, 32, 64);
    if ((lane & 51) == 0)                     // lanes 0,4,8,12
        out[gb0 + (lane >> 2)] = pr + fc_b[0];
}

extern "C" void kernel_launch(void* const* d_in, const int* in_sizes, int n_in,
                              void* d_out, int out_size, void* d_ws, size_t ws_size,
                              hipStream_t stream) {
    const float* x    = (const float*)d_in[0];
    const float* W_ih = (const float*)d_in[1];
    const float* W_hh = (const float*)d_in[2];
    const float* b_ih = (const float*)d_in[3];
    const float* b_hh = (const float*)d_in[4];
    const float* fc_W = (const float*)d_in[5];
    const float* fc_b = (const float*)d_in[6];
    float* out = (float*)d_out;

    const int B = in_sizes[0] / TT;   // 4096 (D == 1)
    dim3 grid(B / BPB), block(NT);
    lstm_dpp<<<grid, block, 0, stream>>>(x, W_ih, W_hh, b_ih, b_hh,
                                         fc_W, fc_b, out);
}

// Round 12
// 367.367 us; speedup vs baseline: 1.2612x; 1.1705x over previous
//
#include <hip/hip_runtime.h>
#include <math.h>

// LSTM fused: H=32, D=1, B=4096, T=1024 — DPP exchange + VGPR-pinned accs.
//
// R8-R11 law: wall ~900-1000 cyc/step regardless of exchange mechanism
// (LDS rw / bpermute / DPP all within 10%) -> the chain is MFMA->extract->act.
// R11 issue audit: ~420 cyc/step of which ~130 cyc is extraction AGPR traffic
// (acc[8] kept in AGPRs at VGPR_Count=88 -> 32 v_accvgpr_read + 24 cndmask,
// all ON the serial chain). R12:
//   1. asm("" : "+v"(acc)) pins each MFMA accumulator quad to ARCH VGPRs
//      (zero-inst class constraint; MFMA writes VGPRs natively on gfx950) ->
//      extraction cndmasks source directly, accvgpr_reads vanish.
//   2. preact q[g] = fmaf(xv,wx,bb) hoisted ABOVE the MFMA block (xv known
//      at step start) -> on-chain preact = 1 v_add per gate.
// Everything else identical to R11: batch b=n>>2, slot rho=n&3, unit pair
// w=4q+rho; pair-permuted A (tile 2g+p = W_hh rows 32g+2m+p); exchange =
// cvt_pkrtz + 4 quad_perm DPP movs; 256 blocks x 4 waves = 1 wave/SIMD.

#define HH 32
#define TT 1024
#define BPW 4               // batches per wave
#define WPB 4               // waves per block
#define BPB (BPW * WPB)     // 16
#define NT 256

typedef _Float16 half8 __attribute__((ext_vector_type(8)));
typedef float    f32x4 __attribute__((ext_vector_type(4)));
typedef int      int4v __attribute__((ext_vector_type(4)));

__device__ __forceinline__ float fast_sigmoid(float x) {
    float e = __builtin_amdgcn_exp2f(x * -1.4426950408889634f);
    return __builtin_amdgcn_rcpf(1.0f + e);
}

__device__ __forceinline__ float fast_tanh(float x) {
    float e = __builtin_amdgcn_exp2f(x * -2.8853900817779268f);
    return fmaf(2.0f, __builtin_amdgcn_rcpf(1.0f + e), -1.0f);
}

__global__ __attribute__((amdgpu_flat_work_group_size(NT, NT),
                          amdgpu_waves_per_eu(1, 2)))
void lstm_vp(const float* __restrict__ x,
             const float* __restrict__ W_ih,
             const float* __restrict__ W_hh,
             const float* __restrict__ b_ih,
             const float* __restrict__ b_hh,
             const float* __restrict__ fc_W,
             const float* __restrict__ fc_b,
             float* __restrict__ out)
{
    __shared__ _Float16 xw[WPB][BPW * TT];   // 32 KB: x fp16, wave-private

    const int tid  = threadIdx.x;
    const int wv   = tid >> 6;
    const int lane = tid & 63;
    const int q    = lane >> 4;          // quad row group
    const int n    = lane & 15;          // MFMA col
    const int b    = n >> 2;             // this lane's batch (0..3)
    const int rho  = n & 3;              // owned slot & C reg component
    const int w    = 4 * q + rho;        // owned unit pair
    const int ue   = 2 * w;
    const int uo   = ue + 1;
    const int gb0  = blockIdx.x * BPB + wv * BPW;

    // ---- stage this wave's 4 x-rows into LDS as fp16 (wave-private) ----
    {
        const float4* xg = (const float4*)(x + (size_t)gb0 * TT);
        #pragma unroll
        for (int it = 0; it < (BPW * TT / 4) / 64; ++it) {
            const float4 v = xg[it * 64 + lane];
            _Float16* dst = &xw[wv][(it * 64 + lane) * 4];
            dst[0] = (_Float16)v.x; dst[1] = (_Float16)v.y;
            dst[2] = (_Float16)v.z; dst[3] = (_Float16)v.w;
        }
    }

    // ---- A-fragments, pair-permuted (R10/R11-validated): tile tau=2g+p,
    //      A row m (=n) = W_hh row 32g + 2m + p;  A[m][k=8q+j] ----
    half8 af[8];
    #pragma unroll
    for (int g = 0; g < 4; ++g) {
        #pragma unroll
        for (int p = 0; p < 2; ++p) {
            const float* arow = W_hh + (size_t)(32 * g + 2 * n + p) * HH + 8 * q;
            #pragma unroll
            for (int j = 0; j < 8; ++j)
                af[2 * g + p][j] = (_Float16)arow[j];
        }
    }

    // ---- per-lane act constants for states (b,ue) and (b,uo) ----
    float wxE[4], bbE[4], wxO[4], bbO[4];
    #pragma unroll
    for (int g = 0; g < 4; ++g) {
        wxE[g] = W_ih[g * HH + ue];
        bbE[g] = b_ih[g * HH + ue] + b_hh[g * HH + ue];
        wxO[g] = W_ih[g * HH + uo];
        bbO[g] = b_ih[g * HH + uo] + b_hh[g * HH + uo];
    }

    float ce = 0.0f, he = 0.0f, co = 0.0f, ho = 0.0f;
    int pki = 0;                          // packed (h_ue, h_uo) fp16x2

    const bool rb0 = (rho & 1) != 0;
    const bool rb1 = (rho & 2) != 0;

    const half8* xp = (const half8*)&xw[wv][b * TT];   // broadcast per quad
    half8 xcur = xp[0];

    #pragma unroll 1
    for (int tc = 0; tc < TT / 8; ++tc) {
        const half8 xv8 = xcur;
        xcur = xp[(tc + 1) & (TT / 8 - 1)];   // prefetch next chunk (off-chain)

        #pragma unroll
        for (int tt = 0; tt < 8; ++tt) {
            // ---- preact bias+input part, OFF the MFMA->act chain ----
            const float xv = (float)xv8[tt];
            float qE[4], qO[4];
            #pragma unroll
            for (int g = 0; g < 4; ++g) {
                qE[g] = fmaf(xv, wxE[g], bbE[g]);
                qO[g] = fmaf(xv, wxO[g], bbO[g]);
            }

            // ---- h exchange: 4 quad_perm broadcasts (pure VALU, no DS) ----
            const int s0 = __builtin_amdgcn_mov_dpp(pki, 0x00, 0xF, 0xF, true);
            const int s1 = __builtin_amdgcn_mov_dpp(pki, 0x55, 0xF, 0xF, true);
            const int s2 = __builtin_amdgcn_mov_dpp(pki, 0xAA, 0xF, 0xF, true);
            const int s3 = __builtin_amdgcn_mov_dpp(pki, 0xFF, 0xF, 0xF, true);
            int4v bi; bi[0] = s0; bi[1] = s1; bi[2] = s2; bi[3] = s3;
            const half8 bf = __builtin_bit_cast(half8, bi);

            const f32x4 zero = {0.0f, 0.0f, 0.0f, 0.0f};
            f32x4 acc[8];
            #pragma unroll
            for (int tau = 0; tau < 8; ++tau) {
                acc[tau] = __builtin_amdgcn_mfma_f32_16x16x32_f16(
                               af[tau], bf, zero, 0, 0, 0);
                // Zero-cost register-class pin: force this quad into ARCH
                // VGPRs so extraction reads need no v_accvgpr_read.
                asm("" : "+v"(acc[tau]));
            }

            // ---- extract: gate g of ue = acc[2g][rho], uo = acc[2g+1][rho] ----
            float ve[4], vo[4];
            #pragma unroll
            for (int g = 0; g < 4; ++g) {
                const f32x4 lo = acc[2 * g];
                const f32x4 hi = acc[2 * g + 1];
                const float l01 = rb0 ? lo[1] : lo[0];
                const float l23 = rb0 ? lo[3] : lo[2];
                ve[g] = rb1 ? l23 : l01;
                const float h01 = rb0 ? hi[1] : hi[0];
                const float h23 = rb0 ? hi[3] : hi[2];
                vo[g] = rb1 ? h23 : h01;
            }

            // ---- act: on-chain preact = 1 add; two independent states ----
            const float pe0 = ve[0] + qE[0];
            const float pe1 = ve[1] + qE[1];
            const float pe2 = ve[2] + qE[2];
            const float pe3 = ve[3] + qE[3];
            const float po0 = vo[0] + qO[0];
            const float po1 = vo[1] + qO[1];
            const float po2 = vo[2] + qO[2];
            const float po3 = vo[3] + qO[3];

            const float giE = fast_sigmoid(pe0);
            const float giO = fast_sigmoid(po0);
            const float gfE = fast_sigmoid(pe1);
            const float gfO = fast_sigmoid(po1);
            const float ggE = fast_tanh(pe2);
            const float ggO = fast_tanh(po2);
            const float goE = fast_sigmoid(pe3);
            const float goO = fast_sigmoid(po3);
            ce = fmaf(gfE, ce, giE * ggE);
            co = fmaf(gfO, co, giO * ggO);
            he = goE * fast_tanh(ce);
            ho = goO * fast_tanh(co);

            // ---- pack for next step's exchange ----
            pki = __builtin_bit_cast(int, __builtin_amdgcn_cvt_pkrtz(he, ho));
        }
    }

    // ---- epilogue: out[b] = fc_W . h + fc_b; batch = lane bits 2,3 ----
    float pr = he * fc_W[ue] + ho * fc_W[uo];
    pr += __shfl_xor(pr, 1, 64);
    pr += __shfl_xor(pr, 2, 64);
    pr += __shfl_xor(pr, 16, 64);
    pr += __shfl_xor(pr, 32, 64);
    if ((lane & 51) == 0)                     // lanes 0,4,8,12
        out[gb0 + (lane >> 2)] = pr + fc_b[0];
}

extern "C" void kernel_launch(void* const* d_in, const int* in_sizes, int n_in,
                              void* d_out, int out_size, void* d_ws, size_t ws_size,
                              hipStream_t stream) {
    const float* x    = (const float*)d_in[0];
    const float* W_ih = (const float*)d_in[1];
    const float* W_hh = (const float*)d_in[2];
    const float* b_ih = (const float*)d_in[3];
    const float* b_hh = (const float*)d_in[4];
    const float* fc_W = (const float*)d_in[5];
    const float* fc_b = (const float*)d_in[6];
    float* out = (float*)d_out;

    const int B = in_sizes[0] / TT;   // 4096 (D == 1)
    dim3 grid(B / BPB), block(NT);
    lstm_vp<<<grid, block, 0, stream>>>(x, W_ih, W_hh, b_ih, b_hh,
                                        fc_W, fc_b, out);
}